// Round 7
// baseline (270.357 us; speedup 1.0000x reference)
//
#include <hip/hip_runtime.h>

#define TDIM 1024
#define DD   263
#define CC   526
#define NFREQ 513
#define PACK 1026
#define KTOP 102

// ---------------- ws layout (float offsets) ----------------
static const size_t WS_EX     = 0;          // 538624 f32
static const size_t WS_W1BF   = 538624;     // 320x288 bf16
static const size_t WS_W2BF   = 584704;
static const size_t WS_WEMT   = 630784;     // 576x288 bf16
static const size_t WS_MASKB  = 1615872;    // 2048x288 bf16
static const size_t WS_HBF    = 2154496;
static const size_t WS_PROJ   = 2693120;    // f32 2048x263
static const size_t WS_XTBF   = 3231744;    // 2x1024x288 bf16
static const size_t WS_CXP    = 3770368;    // f32 2*1026*263 = 539676
static const size_t WS_TWID   = 4310044;    // f32 1026*1024
static const size_t WS_ITBF   = 5360668;    // 1024x1056 bf16
static const size_t WS_CXPT   = 5901340;    // 2x320x1056 bf16
static const size_t WS_TABC   = 6411292;    // 1024
static const size_t WS_TABS   = 6412316;    // 1024
static const size_t WS_SCORE  = 6413340;    // double[2048]
static const size_t WS_MAGM   = 6417436;    // double[1026]
static const size_t WS_MASKT  = 6419488;    // int[2048]
static const size_t WS_IDXT   = 6421536;    // int[204]
static const size_t WS_IDXF   = 6421740;    // int[204]
static const size_t WS_MASKF  = 6421944;    // int[1026]
static const size_t WS_PART   = 6422972;    // partials arena, 4317408 floats
static const size_t WS_TOTAL  = 10740380;   // floats

static const size_t OFF_OUTT = 0;
static const size_t OFF_IDXT = 1077248;
static const size_t OFF_OUTF = 1077452;
static const size_t OFF_IDXF = 2154700;

typedef __bf16 bf16x8_t __attribute__((ext_vector_type(8)));
typedef float  f32x4_t  __attribute__((ext_vector_type(4)));

__device__ __forceinline__ unsigned short f2bf(float f) {
    unsigned int u = __float_as_uint(f);
    unsigned int r = (u + 0x7fffu + ((u >> 16) & 1u)) >> 16;
    return (unsigned short)r;
}

__device__ __forceinline__ float pe_val(int t, int d) {
    const float sc = (float)(-9.210340371976184 / 263.0);  // -ln(10000)/D
    int j = d >> 1;
    float div = expf((float)(2 * j) * sc);
    float a = (float)t * div;
    return (d & 1) ? cosf(a) : sinf(a);
}

// ---------------- split-K pipelined tiled f32 GEMM (ranking-feeding GEMMs) ----------------
#define KCH 16
template<int TRANSB>
__global__ __launch_bounds__(256) void gemm_sk(const float* __restrict__ A,
                                               const float* __restrict__ B,
                                               float* __restrict__ part,
                                               int M, int N, int K, int S,
                                               long sB, long MN)
{
    __shared__ float As[2][KCH][68];
    __shared__ float Bs[2][KCH][68];
    const int s     = blockIdx.z % S;
    const int batch = blockIdx.z / S;
    B    += (size_t)batch * (size_t)sB;
    part += (size_t)blockIdx.z * (size_t)MN;
    const int tid  = threadIdx.x;
    const int row0 = blockIdx.x * 64, col0 = blockIdx.y * 64;
    const int ty = tid >> 4, tx = tid & 15;
    const int lm = tid >> 2;
    const int lk = (tid & 3) * 4;
    const int bk = tid >> 4;
    const int bn = (tid & 15) * 4;
    float acc[4][4] = {};
    float ra[4], rb[4];

    const int nk  = (K + KCH - 1) / KCH;
    const int ks  = (nk + S - 1) / S;
    const int it0 = s * ks;
    const int it1 = min(nk, it0 + ks);

    auto loadT = [&](int k0) {
        {
            int gm = row0 + lm;
            const float* p = A + (size_t)gm * K;
            bool mok = (gm < M);
#pragma unroll
            for (int j = 0; j < 4; j++) {
                int gk = k0 + lk + j;
                ra[j] = (mok && gk < K) ? p[gk] : 0.0f;
            }
        }
        if (TRANSB) {
            int gn = col0 + lm;
            const float* p = B + (size_t)gn * K;
            bool nok = (gn < N);
#pragma unroll
            for (int j = 0; j < 4; j++) {
                int gk = k0 + lk + j;
                rb[j] = (nok && gk < K) ? p[gk] : 0.0f;
            }
        } else {
            int gk = k0 + bk;
            const float* p = B + (size_t)gk * N;
            bool kok = (gk < K);
#pragma unroll
            for (int j = 0; j < 4; j++) {
                int gn = col0 + bn + j;
                rb[j] = (kok && gn < N) ? p[gn] : 0.0f;
            }
        }
    };
    auto storeT = [&](int buf) {
#pragma unroll
        for (int j = 0; j < 4; j++) As[buf][lk + j][lm] = ra[j];
        if (TRANSB) {
#pragma unroll
            for (int j = 0; j < 4; j++) Bs[buf][lk + j][lm] = rb[j];
        } else {
            *(float4*)&Bs[buf][bk][bn] = make_float4(rb[0], rb[1], rb[2], rb[3]);
        }
    };

    if (it0 < it1) {
        loadT(it0 * KCH);
        storeT(0);
        __syncthreads();
        const int nloc = it1 - it0;
        for (int it = 0; it < nloc; ++it) {
            const int cur = it & 1;
            if (it + 1 < nloc) loadT((it0 + it + 1) * KCH);
#pragma unroll
            for (int kk = 0; kk < KCH; kk++) {
                float4 a4 = *(const float4*)&As[cur][kk][ty * 4];
                float4 b4 = *(const float4*)&Bs[cur][kk][tx * 4];
                float av[4] = {a4.x, a4.y, a4.z, a4.w};
                float bv[4] = {b4.x, b4.y, b4.z, b4.w};
#pragma unroll
                for (int i = 0; i < 4; i++)
#pragma unroll
                    for (int j = 0; j < 4; j++)
                        acc[i][j] += av[i] * bv[j];
            }
            if (it + 1 < nloc) {
                storeT(cur ^ 1);
                __syncthreads();
            }
        }
    }

#pragma unroll
    for (int i = 0; i < 4; i++) {
        int r = row0 + ty * 4 + i;
        if (r >= M) continue;
#pragma unroll
        for (int j = 0; j < 4; j++) {
            int c = col0 + tx * 4 + j;
            if (c >= N) continue;
            part[(size_t)r * N + c] = acc[i][j];
        }
    }
}

// reduce S partials + epilogue for f32 GEMMs. EPI: 0 none, 3 bias+pe
template<int EPI>
__global__ __launch_bounds__(256) void reduce_k(const float* __restrict__ part,
                                                const float* __restrict__ bias,
                                                float* __restrict__ C,
                                                int N, int S, long MN, long sC, long total)
{
    long g = (long)blockIdx.x * 256 + threadIdx.x;
    if (g >= total) return;
    long batch = g / MN;
    long e     = g - batch * MN;
    const float* p = part + batch * (long)S * MN + e;
    float v = 0.0f;
    for (int s2 = 0; s2 < S; s2++) v += p[(size_t)s2 * MN];
    int r = (int)(e / N), c = (int)(e - (long)r * N);
    if (EPI == 3) { v += bias[c] + pe_val(r & (TDIM - 1), c); }
    C[batch * sC + e] = v;
}

// ---------------- split-K bf16 MFMA GEMM: part[z] = A @ Bt^T (k-chunk z%S) ----------------
// A [M x SA] bf16, Bt [Npad x SA] bf16 (z/S batches Bt). Tile 64x64, 4 waves 2x2.
__global__ __launch_bounds__(256) void gemm_mfma_sk(const unsigned short* __restrict__ A,
                                                    const unsigned short* __restrict__ Bt,
                                                    float* __restrict__ part,
                                                    int N, int SA, int S,
                                                    long sBt, long MN)
{
    __shared__ unsigned short As[2][64][40];
    __shared__ unsigned short Bs[2][64][40];
    const int s = blockIdx.z % S, batch = blockIdx.z / S;
    Bt   += (size_t)batch * (size_t)sBt;
    part += (size_t)blockIdx.z * (size_t)MN;
    const int tid  = threadIdx.x;
    const int row0 = blockIdx.x * 64, col0 = blockIdx.y * 64;
    const int wid = tid >> 6, lane = tid & 63;
    const int wr = wid >> 1, wc = wid & 1;
    const int srow = tid >> 2, skoff = (tid & 3) * 8;
    const int fl = lane & 15, fh = lane >> 4;
    f32x4_t acc[2][2];
#pragma unroll
    for (int i = 0; i < 2; i++)
#pragma unroll
        for (int j = 0; j < 2; j++) acc[i][j] = (f32x4_t){0.f, 0.f, 0.f, 0.f};

    const int nk = SA / 32;
    const int ks = (nk + S - 1) / S;
    const int it0 = s * ks;
    const int it1 = min(nk, it0 + ks);
    const unsigned short* pa = A  + (size_t)(row0 + srow) * SA + skoff;
    const unsigned short* pb = Bt + (size_t)(col0 + srow) * SA + skoff;

    if (it0 < it1) {
        bf16x8_t ra = *(const bf16x8_t*)(pa + (size_t)it0 * 32);
        bf16x8_t rb = *(const bf16x8_t*)(pb + (size_t)it0 * 32);
        *(bf16x8_t*)(&As[0][srow][skoff]) = ra;
        *(bf16x8_t*)(&Bs[0][srow][skoff]) = rb;
        __syncthreads();
        const int nloc = it1 - it0;
        for (int it = 0; it < nloc; ++it) {
            const int cur = it & 1;
            if (it + 1 < nloc) {
                ra = *(const bf16x8_t*)(pa + (size_t)(it0 + it + 1) * 32);
                rb = *(const bf16x8_t*)(pb + (size_t)(it0 + it + 1) * 32);
            }
            bf16x8_t fa0 = *(const bf16x8_t*)(&As[cur][wr * 32 + fl][fh * 8]);
            bf16x8_t fa1 = *(const bf16x8_t*)(&As[cur][wr * 32 + 16 + fl][fh * 8]);
            bf16x8_t fb0 = *(const bf16x8_t*)(&Bs[cur][wc * 32 + fl][fh * 8]);
            bf16x8_t fb1 = *(const bf16x8_t*)(&Bs[cur][wc * 32 + 16 + fl][fh * 8]);
            acc[0][0] = __builtin_amdgcn_mfma_f32_16x16x32_bf16(fa0, fb0, acc[0][0], 0, 0, 0);
            acc[0][1] = __builtin_amdgcn_mfma_f32_16x16x32_bf16(fa0, fb1, acc[0][1], 0, 0, 0);
            acc[1][0] = __builtin_amdgcn_mfma_f32_16x16x32_bf16(fa1, fb0, acc[1][0], 0, 0, 0);
            acc[1][1] = __builtin_amdgcn_mfma_f32_16x16x32_bf16(fa1, fb1, acc[1][1], 0, 0, 0);
            if (it + 1 < nloc) {
                *(bf16x8_t*)(&As[cur ^ 1][srow][skoff]) = ra;
                *(bf16x8_t*)(&Bs[cur ^ 1][srow][skoff]) = rb;
                __syncthreads();
            }
        }
    }

#pragma unroll
    for (int fi = 0; fi < 2; fi++)
#pragma unroll
        for (int fj = 0; fj < 2; fj++)
#pragma unroll
            for (int r = 0; r < 4; r++) {
                int m = row0 + wr * 32 + fi * 16 + fh * 4 + r;
                int n = col0 + wc * 32 + fj * 16 + fl;
                if (n < N) part[(size_t)m * N + n] = acc[fi][fj][r];
            }
}

// reduce S MFMA partials + epilogue. EPI: 0 ->f32; 1 bias+gelu->bf16(pad0);
// 2 bias+sigmoid->f32; 4 ->bf16(pad0). g enumerates (b, m, n<NOUT).
template<int EPI>
__global__ __launch_bounds__(256) void reduce2_k(const float* __restrict__ part,
                                                 const float* __restrict__ bias,
                                                 void* __restrict__ outp,
                                                 int N, int NOUT, int S, int M, long total)
{
    long g = (long)blockIdx.x * 256 + threadIdx.x;
    if (g >= total) return;
    int n = (int)(g % NOUT);
    long rm = g / NOUT;
    int m = (int)(rm % M);
    int b = (int)(rm / M);
    long MN = (long)M * N;
    float v = 0.0f;
    if (n < N) {
        const float* p = part + (long)b * S * MN + (long)m * N + n;
        for (int s2 = 0; s2 < S; s2++) v += p[(long)s2 * MN];
    }
    if (EPI == 0) {
        ((float*)outp)[g] = v;
    } else if (EPI == 1) {
        if (n < N) { v += bias[n]; v = 0.5f * v * (1.0f + erff(v * 0.70710678118654752f)); }
        ((unsigned short*)outp)[g] = (n < N) ? f2bf(v) : (unsigned short)0;
    } else if (EPI == 2) {
        v += bias[n];
        ((float*)outp)[g] = 1.0f / (1.0f + expf(-v));
    } else {
        ((unsigned short*)outp)[g] = (n < N) ? f2bf(v) : (unsigned short)0;
    }
}

// ---------------- glue kernels ----------------
__global__ void zero_masks_k(int* maskt, int* maskf) {
    int i = blockIdx.x * 256 + threadIdx.x;
    if (i < 2 * TDIM) maskt[i] = 0;
    if (i < PACK) maskf[i] = 0;
}

__global__ void tab_k(float* tabc, float* tabs) {
    int i = blockIdx.x * 256 + threadIdx.x;
    if (i >= 1024) return;
    double ang = (double)i * (3.14159265358979323846 * 2.0 / 1024.0);
    tabc[i] = (float)cos(ang);
    tabs[i] = (float)sin(ang);
}

__global__ void twid_fill_k(const float* __restrict__ tabc, const float* __restrict__ tabs,
                            float* __restrict__ Tw) {
    int row = blockIdx.x;
    for (int t = threadIdx.x; t < 1024; t += 256) {
        float v;
        if (row < NFREQ) v = tabc[(row * t) & 1023];
        else             v = -tabs[((row - NFREQ) * t) & 1023];
        Tw[(size_t)row * 1024 + t] = v;
    }
}

__global__ void itwid_fill_bf_k(const float* __restrict__ tabc, const float* __restrict__ tabs,
                                unsigned short* __restrict__ IT) {
    int t = blockIdx.x;
    for (int col = threadIdx.x; col < 1056; col += 256) {
        float v = 0.0f;
        if (col < NFREQ) {
            int k = col;
            float w = (k == 0 || k == 512) ? 1.0f : 2.0f;
            v = (w * (1.0f / 1024.0f)) * tabc[(k * t) & 1023];
        } else if (col < PACK) {
            int k = col - NFREQ;
            v = (k == 0 || k == 512) ? 0.0f : (-2.0f / 1024.0f) * tabs[(k * t) & 1023];
        }
        IT[(size_t)t * 1056 + col] = f2bf(v);
    }
}

// fused weight conversions (writes ALL pad zeros; replaces memsets)
__global__ void conv_weights_k(const float* __restrict__ W1t, const float* __restrict__ W2t,
                               const float* __restrict__ W_emb,
                               unsigned short* __restrict__ w1b, unsigned short* __restrict__ w2b,
                               unsigned short* __restrict__ wemT) {
    int r = blockIdx.x;   // 0..1215
    if (r < 640) {
        int rr = r & 319;
        const float* src = (r < 320) ? W1t : W2t;
        unsigned short* dst = (r < 320) ? w1b : w2b;
        for (int c = threadIdx.x; c < 288; c += 256) {
            float v = (rr < DD && c < DD) ? src[(size_t)rr * DD + c] : 0.0f;
            dst[(size_t)rr * 288 + c] = f2bf(v);
        }
    } else {
        int rr = r - 640;  // 0..575 : wemT row rr = column rr of W_emb
        for (int c = threadIdx.x; c < 288; c += 256) {
            float v = (rr < CC && c < DD) ? W_emb[(size_t)c * CC + rr] : 0.0f;
            wemT[(size_t)rr * 288 + c] = f2bf(v);
        }
    }
}

__global__ __launch_bounds__(64) void sliding_score_k(const float* __restrict__ ex,
                                                      double* __restrict__ score)
{
    const int ib = blockIdx.x;
    const int t = ib & (TDIM - 1);
    const int t0 = max(0, t - 24);
    const int nt = t - t0 + 1;
    const float cnt = (float)nt;
    const int lane = threadIdx.x;
    const float* base = ex + ((size_t)(ib - t) + t0) * DD;
    double ms = 0.0, vs = 0.0;
    for (int d = lane; d < DD; d += 64) {
        float s1 = 0.0f, s2 = 0.0f;
        for (int r = 0; r < nt; r++) {
            float v = base[(size_t)r * DD + d];
            s1 += v;
            s2 += v * v;
        }
        float m1 = s1 / cnt;
        float var = s2 / cnt - m1 * m1;
        ms += (double)m1;
        vs += (double)var;
    }
#pragma unroll
    for (int off = 32; off; off >>= 1) { ms += __shfl_xor(ms, off); vs += __shfl_xor(vs, off); }
    if (lane == 0) score[ib] = vs / (ms + (double)1e-6f);
}

__global__ __launch_bounds__(512) void topk_sort_k(const double* __restrict__ score,
                                                   int n, int kcount,
                                                   float* __restrict__ out_f,
                                                   int* __restrict__ out_i,
                                                   int* __restrict__ mask)
{
    __shared__ double sv[1024];
    __shared__ int    si[1024];
    const int b = blockIdx.x, tid = threadIdx.x;
    const double* s = score + (size_t)b * n;
    for (int i = tid; i < 1024; i += 512) {
        sv[i] = (i < n) ? s[i] : -1.0e300;
        si[i] = i;
    }
    __syncthreads();
    for (int k = 2; k <= 1024; k <<= 1) {
        for (int j = k >> 1; j > 0; j >>= 1) {
            for (int t = tid; t < 1024; t += 512) {
                int l = t ^ j;
                if (l > t) {
                    double v0 = sv[t], v1 = sv[l];
                    int i0 = si[t], i1 = si[l];
                    bool g = (v0 > v1) || (v0 == v1 && i0 < i1);
                    bool wrong = ((t & k) == 0) ? !g : g;
                    if (wrong) {
                        sv[t] = v1; sv[l] = v0;
                        si[t] = i1; si[l] = i0;
                    }
                }
            }
            __syncthreads();
        }
    }
    for (int t = tid; t < kcount; t += 512) {
        int bi = si[t];
        out_f[(size_t)b * kcount + t] = (float)bi;
        out_i[b * kcount + t] = bi;
        mask[b * n + bi] = 1;
    }
}

__global__ void build_masked_k(const float* __restrict__ ex, const float* __restrict__ ttok,
                               const int* __restrict__ maskt, unsigned short* __restrict__ mb) {
    int bt = blockIdx.x;
    int d = threadIdx.x;
    if (d >= 288) return;
    float v = 0.0f;
    if (d < DD) v = maskt[bt] ? ttok[d] : ex[(size_t)bt * DD + d];
    mb[(size_t)bt * 288 + d] = f2bf(v);
}

__global__ void select_k(const int* __restrict__ maskt, const float* __restrict__ proj,
                         unsigned short* __restrict__ mb) {
    int bt = blockIdx.x;
    int d = threadIdx.x;
    if (d >= DD) return;
    if (!maskt[bt]) mb[(size_t)bt * 288 + d] = f2bf(proj[(size_t)bt * DD + d]);
}

__global__ void mag_k(const float* __restrict__ cxp, double* __restrict__ magm) {
    int ib = blockIdx.x;
    int b = ib / NFREQ, k = ib % NFREQ;
    int lane = threadIdx.x;
    const float* re = cxp + ((size_t)b * PACK + k) * DD;
    const float* im = cxp + ((size_t)b * PACK + NFREQ + k) * DD;
    double acc = 0.0;
    for (int d = lane; d < DD; d += 64) {
        float r = re[d], i = im[d];
        acc += (double)sqrtf(r * r + i * i);
    }
#pragma unroll
    for (int off = 32; off; off >>= 1) acc += __shfl_xor(acc, off);
    if (lane == 0) magm[ib] = acc / (double)DD;
}

__global__ void fmask_apply_k(float* __restrict__ cxp, const int* __restrict__ idxf,
                              const float* __restrict__ tokr, const float* __restrict__ toki) {
    int b = blockIdx.x / KTOP, j = blockIdx.x % KTOP;
    int d = threadIdx.x;
    if (d >= DD) return;
    int k = idxf[b * KTOP + j];
    float* base = cxp + (size_t)b * PACK * DD;
    base[(size_t)k * DD + d] = tokr[d];
    base[(size_t)(NFREQ + k) * DD + d] = toki[d];
}

// cxp f32 [2][1026][263] -> cxpT bf16 [2][320][1056] (full fill incl. pads)
__global__ void conv_cxpT_k(const float* __restrict__ cxp, unsigned short* __restrict__ cxpT) {
    int b = blockIdx.x / 320, n = blockIdx.x % 320;
    unsigned short* dst = cxpT + ((size_t)b * 320 + n) * 1056;
    const float* src = cxp + (size_t)b * PACK * DD + n;
    for (int c = threadIdx.x; c < 1056; c += 256) {
        float v = (n < DD && c < PACK) ? src[(size_t)c * DD] : 0.0f;
        dst[c] = f2bf(v);
    }
}

// ---------------- launch ----------------
extern "C" void kernel_launch(void* const* d_in, const int* in_sizes, int n_in,
                              void* d_out, int out_size, void* d_ws, size_t ws_size,
                              hipStream_t stream) {
    (void)in_sizes; (void)n_in; (void)out_size;
    const float* x      = (const float*)d_in[0];
    const float* W_emb  = (const float*)d_in[1];
    const float* b_emb  = (const float*)d_in[2];
    const float* ttok   = (const float*)d_in[3];
    const float* W1t    = (const float*)d_in[4];
    const float* b1t    = (const float*)d_in[5];
    const float* W2t    = (const float*)d_in[6];
    const float* b2t    = (const float*)d_in[7];
    const float* ftr    = (const float*)d_in[8];
    const float* fti    = (const float*)d_in[9];
    float* out = (float*)d_out;
    float* ws  = (float*)d_ws;

    float* ex     = ws + WS_EX;
    float* proj   = ws + WS_PROJ;
    float* cxp    = ws + WS_CXP;
    float* Twid   = ws + WS_TWID;
    float* tabc   = ws + WS_TABC;
    float* tabs   = ws + WS_TABS;
    double* score = (double*)(ws + WS_SCORE);
    double* magm  = (double*)(ws + WS_MAGM);
    int* maskt    = (int*)(ws + WS_MASKT);
    int* idxt     = (int*)(ws + WS_IDXT);
    int* idxf     = (int*)(ws + WS_IDXF);
    int* maskf    = (int*)(ws + WS_MASKF);
    float* partw  = ws + WS_PART;
    unsigned short* w1b   = (unsigned short*)(ws + WS_W1BF);
    unsigned short* w2b   = (unsigned short*)(ws + WS_W2BF);
    unsigned short* wemT  = (unsigned short*)(ws + WS_WEMT);
    unsigned short* maskb = (unsigned short*)(ws + WS_MASKB);
    unsigned short* hb    = (unsigned short*)(ws + WS_HBF);
    unsigned short* xtb   = (unsigned short*)(ws + WS_XTBF);
    unsigned short* itb   = (unsigned short*)(ws + WS_ITBF);
    unsigned short* cxpT  = (unsigned short*)(ws + WS_CXPT);

    const bool big = ws_size >= (size_t)WS_TOTAL * 4;

    // init + tables + weight conversions (producers write all pad zeros)
    zero_masks_k<<<8, 256, 0, stream>>>(maskt, maskf);
    tab_k<<<4, 256, 0, stream>>>(tabc, tabs);
    twid_fill_k<<<PACK, 256, 0, stream>>>(tabc, tabs, Twid);
    itwid_fill_bf_k<<<TDIM, 256, 0, stream>>>(tabc, tabs, itb);
    conv_weights_k<<<1216, 256, 0, stream>>>(W1t, W2t, W_emb, w1b, w2b, wemT);

    // ex = x @ W_emb^T + b_emb + pe  (f32 split-K; feeds both rankings)
    {
        int S = big ? 8 : 1;
        float* pp = big ? partw : ex;
        long MN = (long)2048 * DD;
        gemm_sk<1><<<dim3(32, 5, S), 256, 0, stream>>>(x, W_emb, pp, 2048, DD, CC, S, 0, MN);
        reduce_k<3><<<(int)((MN + 255) / 256), 256, 0, stream>>>(pp, b_emb, ex, DD, S, MN, 0, MN);
    }

    // temporal score -> topk
    sliding_score_k<<<2048, 64, 0, stream>>>(ex, score);
    topk_sort_k<<<2, 512, 0, stream>>>(score, TDIM, KTOP, out + OFF_IDXT, idxt, maskt);

    // masked -> h -> proj -> select -> out_t   [value GEMMs: split-K MFMA]
    build_masked_k<<<2048, 320, 0, stream>>>(ex, ttok, maskt, maskb);
    {
        int S = big ? 3 : 1;
        float* pp = big ? partw : proj;
        long MN = (long)2048 * DD;
        gemm_mfma_sk<<<dim3(32, 5, S), 256, 0, stream>>>(maskb, w1b, pp, DD, 288, S, 0, MN);
        reduce2_k<1><<<(int)((2048L * 288 + 255) / 256), 256, 0, stream>>>(pp, b1t, hb, DD, 288, S, 2048, 2048L * 288);
        gemm_mfma_sk<<<dim3(32, 5, S), 256, 0, stream>>>(hb, w2b, pp, DD, 288, S, 0, MN);
        reduce2_k<2><<<(int)((MN + 255) / 256), 256, 0, stream>>>(pp, b2t, proj, DD, DD, S, 2048, MN);
    }
    select_k<<<2048, 320, 0, stream>>>(maskt, proj, maskb);
    {
        int S = big ? 3 : 1;
        float* pp = big ? partw : (out + OFF_OUTT);
        long MN = (long)2048 * CC;
        gemm_mfma_sk<<<dim3(32, 9, S), 256, 0, stream>>>(maskb, wemT, pp, CC, 288, S, 0, MN);
        reduce2_k<0><<<(int)((MN + 255) / 256), 256, 0, stream>>>(pp, nullptr, out + OFF_OUTT, CC, CC, S, 2048, MN);
    }

    // forward DFT (f32 split-K; feeds mag ranking): cxp[b] = Twid @ ex[b]
    {
        int S = big ? 8 : 1;
        float* pp = big ? partw : cxp;
        long MN = (long)PACK * DD;
        gemm_sk<0><<<dim3(17, 5, 2 * S), 256, 0, stream>>>(Twid, ex, pp, PACK, DD, 1024, S,
                                                           (long)TDIM * DD, MN);
        reduce_k<0><<<(int)((2 * MN + 255) / 256), 256, 0, stream>>>(pp, nullptr, cxp, DD, S, MN, MN, 2 * MN);
    }
    mag_k<<<2 * NFREQ, 64, 0, stream>>>(cxp, magm);
    topk_sort_k<<<2, 512, 0, stream>>>(magm, NFREQ, KTOP, out + OFF_IDXF, idxf, maskf);
    fmask_apply_k<<<2 * KTOP, 320, 0, stream>>>(cxp, idxf, ftr, fti);
    conv_cxpT_k<<<640, 256, 0, stream>>>(cxp, cxpT);

    // inverse DFT (split-K MFMA): xt[b] = ITwid @ cxp[b]^T^T -> xtb
    {
        int S = big ? 8 : 1;
        float* pp = big ? partw : cxp;   // cxp free after conv_cxpT
        long MN = (long)1024 * DD;
        gemm_mfma_sk<<<dim3(16, 5, 2 * S), 256, 0, stream>>>(itb, cxpT, pp, DD, 1056, S,
                                                             (long)320 * 1056, MN);
        reduce2_k<4><<<(int)((2L * 1024 * 288 + 255) / 256), 256, 0, stream>>>(pp, nullptr, xtb, DD, 288, S, 1024, 2L * 1024 * 288);
    }
    // out_f = xt @ W_emb
    {
        int S = big ? 3 : 1;
        float* pp = big ? partw : (out + OFF_OUTF);
        long MN = (long)2048 * CC;
        gemm_mfma_sk<<<dim3(32, 9, S), 256, 0, stream>>>(xtb, wemT, pp, CC, 288, S, 0, MN);
        reduce2_k<0><<<(int)((MN + 255) / 256), 256, 0, stream>>>(pp, nullptr, out + OFF_OUTF, CC, CC, S, 2048, MN);
    }
}

// Round 9
// 251.153 us; speedup vs baseline: 1.0765x; 1.0765x over previous
//
#include <hip/hip_runtime.h>

#define TDIM 1024
#define DD   263
#define CC   526
#define NFREQ 513
#define PACK 1026
#define KTOP 102

// ---------------- ws layout (float offsets) ----------------
static const size_t WS_EX     = 0;          // 538624 f32
static const size_t WS_W1BF   = 538624;     // 320x288 bf16
static const size_t WS_W2BF   = 584704;
static const size_t WS_WEMT   = 630784;     // 576x288 bf16
static const size_t WS_MASKB  = 1615872;    // 2048x288 bf16
static const size_t WS_HBF    = 2154496;
static const size_t WS_PROJ   = 2693120;    // f32 2048x263
static const size_t WS_XTBF   = 3231744;    // 2x1024x288 bf16
static const size_t WS_CXP    = 3770368;    // f32 2*1026*263 = 539676
static const size_t WS_TWID   = 4310044;    // f32 1026*1024
static const size_t WS_ITBF   = 5360668;    // 1024x1056 bf16
static const size_t WS_CXPT   = 5901340;    // 2x320x1056 bf16
static const size_t WS_TABC   = 6411292;    // 1024
static const size_t WS_TABS   = 6412316;    // 1024
static const size_t WS_SCORE  = 6413340;    // double[2048]
static const size_t WS_MAGM   = 6417436;    // double[1026]
static const size_t WS_MASKT  = 6419488;    // int[2048]
static const size_t WS_IDXT   = 6421536;    // int[204]
static const size_t WS_IDXF   = 6421740;    // int[204]
static const size_t WS_MASKF  = 6421944;    // int[1026]
static const size_t WS_PART   = 6422972;    // partials arena, 4317408 floats
static const size_t WS_TOTAL  = 10740380;   // floats

static const size_t OFF_OUTT = 0;
static const size_t OFF_IDXT = 1077248;
static const size_t OFF_OUTF = 1077452;
static const size_t OFF_IDXF = 2154700;

typedef __bf16 bf16x8_t __attribute__((ext_vector_type(8)));
typedef float  f32x4_t  __attribute__((ext_vector_type(4)));

__device__ __forceinline__ unsigned short f2bf(float f) {
    unsigned int u = __float_as_uint(f);
    unsigned int r = (u + 0x7fffu + ((u >> 16) & 1u)) >> 16;
    return (unsigned short)r;
}

__device__ __forceinline__ float pe_val(int t, int d) {
    const float sc = (float)(-9.210340371976184 / 263.0);  // -ln(10000)/D
    int j = d >> 1;
    float div = expf((float)(2 * j) * sc);
    float a = (float)t * div;
    return (d & 1) ? cosf(a) : sinf(a);
}

// ---------------- split-K f32 GEMM, 128x128 tile, 8x8 per-thread ----------------
// part[z*MN + r*N + c] = partial sum over k-chunk (z%S). z/S batches B.
// TRANSB=1: B is [N,K] row-major. 0.5 B LDS per FLOP (vs 2.0 for 4x4 tile).
#define KC8 8
template<int TRANSB>
__global__ __launch_bounds__(256) void gemm_sk8(const float* __restrict__ A,
                                                const float* __restrict__ B,
                                                float* __restrict__ part,
                                                int M, int N, int K, int S,
                                                long sB, long MN)
{
    __shared__ float As[2][KC8][132];
    __shared__ float Bs[2][KC8][132];
    const int s = blockIdx.z % S, batch = blockIdx.z / S;
    B    += (size_t)batch * (size_t)sB;
    part += (size_t)blockIdx.z * (size_t)MN;
    const int tid  = threadIdx.x;
    const int row0 = blockIdx.x * 128, col0 = blockIdx.y * 128;
    const int ty = tid >> 4, tx = tid & 15;
    const int ar = tid >> 1;            // 0..127
    const int ak = (tid & 1) * 4;       // 0 or 4
    const int bk = tid >> 5;            // 0..7
    const int bn = (tid & 31) * 4;      // 0..124
    float acc[8][8] = {};
    float ra[4], rb[4];

    const int nk  = (K + KC8 - 1) / KC8;
    const int ks  = (nk + S - 1) / S;
    const int it0 = s * ks;
    const int it1 = min(nk, it0 + ks);

    auto loadT = [&](int k0) {
        {
            int gm = row0 + ar;
            const float* p = A + (size_t)gm * K;
            bool ok = (gm < M);
#pragma unroll
            for (int j = 0; j < 4; j++) {
                int gk = k0 + ak + j;
                ra[j] = (ok && gk < K) ? p[gk] : 0.0f;
            }
        }
        if (TRANSB) {
            int gn = col0 + ar;
            const float* p = B + (size_t)gn * K;
            bool ok = (gn < N);
#pragma unroll
            for (int j = 0; j < 4; j++) {
                int gk = k0 + ak + j;
                rb[j] = (ok && gk < K) ? p[gk] : 0.0f;
            }
        } else {
            int gk = k0 + bk;
            const float* p = B + (size_t)gk * N;
            bool ok = (gk < K);
#pragma unroll
            for (int j = 0; j < 4; j++) {
                int gn = col0 + bn + j;
                rb[j] = (ok && gn < N) ? p[gn] : 0.0f;
            }
        }
    };
    auto storeT = [&](int buf) {
#pragma unroll
        for (int j = 0; j < 4; j++) As[buf][ak + j][ar] = ra[j];
        if (TRANSB) {
#pragma unroll
            for (int j = 0; j < 4; j++) Bs[buf][ak + j][ar] = rb[j];
        } else {
            *(float4*)&Bs[buf][bk][bn] = make_float4(rb[0], rb[1], rb[2], rb[3]);
        }
    };

    if (it0 < it1) {
        loadT(it0 * KC8);
        storeT(0);
        __syncthreads();
        const int nloc = it1 - it0;
        for (int it = 0; it < nloc; ++it) {
            const int cur = it & 1;
            if (it + 1 < nloc) loadT((it0 + it + 1) * KC8);
#pragma unroll
            for (int kk = 0; kk < KC8; kk++) {
                float4 alo = *(const float4*)&As[cur][kk][ty * 4];
                float4 ahi = *(const float4*)&As[cur][kk][64 + ty * 4];
                float4 blo = *(const float4*)&Bs[cur][kk][tx * 4];
                float4 bhi = *(const float4*)&Bs[cur][kk][64 + tx * 4];
                float av[8] = {alo.x, alo.y, alo.z, alo.w, ahi.x, ahi.y, ahi.z, ahi.w};
                float bv[8] = {blo.x, blo.y, blo.z, blo.w, bhi.x, bhi.y, bhi.z, bhi.w};
#pragma unroll
                for (int i = 0; i < 8; i++)
#pragma unroll
                    for (int j = 0; j < 8; j++)
                        acc[i][j] += av[i] * bv[j];
            }
            if (it + 1 < nloc) {
                storeT(cur ^ 1);
                __syncthreads();
            }
        }
    }

#pragma unroll
    for (int i = 0; i < 8; i++) {
        int r = row0 + ((i < 4) ? (ty * 4 + i) : (64 + ty * 4 + i - 4));
        if (r >= M) continue;
#pragma unroll
        for (int j = 0; j < 8; j++) {
            int c = col0 + ((j < 4) ? (tx * 4 + j) : (64 + tx * 4 + j - 4));
            if (c >= N) continue;
            part[(size_t)r * N + c] = acc[i][j];
        }
    }
}

// reduce S partials + epilogue for f32 GEMMs. EPI: 0 none, 3 bias+pe
template<int EPI>
__global__ __launch_bounds__(256) void reduce_k(const float* __restrict__ part,
                                                const float* __restrict__ bias,
                                                float* __restrict__ C,
                                                int N, int S, long MN, long sC, long total)
{
    long g = (long)blockIdx.x * 256 + threadIdx.x;
    if (g >= total) return;
    long batch = g / MN;
    long e     = g - batch * MN;
    const float* p = part + batch * (long)S * MN + e;
    float v = 0.0f;
    for (int s2 = 0; s2 < S; s2++) v += p[(size_t)s2 * MN];
    int r = (int)(e / N), c = (int)(e - (long)r * N);
    if (EPI == 3) { v += bias[c] + pe_val(r & (TDIM - 1), c); }
    C[batch * sC + e] = v;
}

// ---------------- bf16 MFMA GEMM: C = A @ Bt^T (direct epilogue, writes pads) ----------------
// A [M x SA] bf16, Bt [Npad x SA] bf16. Tile 64x64, 4 waves 2x2.
// EPI: 0 ->f32 (n<N only); 1 bias+gelu->bf16 (zero pads to NC); 2 bias+sigmoid->f32;
//      3 ->bf16 (zero pads to NC)
template<int EPI>
__global__ __launch_bounds__(256) void gemm_mfma(const unsigned short* __restrict__ A,
                                                 const unsigned short* __restrict__ Bt,
                                                 const float* __restrict__ bias,
                                                 void* __restrict__ Cv,
                                                 int N, int SA, int NC,
                                                 long sBt, long sC)
{
    __shared__ unsigned short As[2][64][40];
    __shared__ unsigned short Bs[2][64][40];
    const int tid  = threadIdx.x;
    const int row0 = blockIdx.x * 64, col0 = blockIdx.y * 64;
    Bt += (size_t)blockIdx.z * (size_t)sBt;
    const long co = (long)blockIdx.z * sC;
    const int wid = tid >> 6, lane = tid & 63;
    const int wr = wid >> 1, wc = wid & 1;
    const int srow = tid >> 2, skoff = (tid & 3) * 8;
    const int fl = lane & 15, fh = lane >> 4;
    f32x4_t acc[2][2];
#pragma unroll
    for (int i = 0; i < 2; i++)
#pragma unroll
        for (int j = 0; j < 2; j++) acc[i][j] = (f32x4_t){0.f, 0.f, 0.f, 0.f};

    bf16x8_t ra, rb;
    const int nk = SA / 32;
    const unsigned short* pa = A  + (size_t)(row0 + srow) * SA + skoff;
    const unsigned short* pb = Bt + (size_t)(col0 + srow) * SA + skoff;

    ra = *(const bf16x8_t*)(pa);
    rb = *(const bf16x8_t*)(pb);
    *(bf16x8_t*)(&As[0][srow][skoff]) = ra;
    *(bf16x8_t*)(&Bs[0][srow][skoff]) = rb;
    __syncthreads();
    for (int it = 0; it < nk; ++it) {
        const int cur = it & 1;
        if (it + 1 < nk) {
            ra = *(const bf16x8_t*)(pa + (size_t)(it + 1) * 32);
            rb = *(const bf16x8_t*)(pb + (size_t)(it + 1) * 32);
        }
        bf16x8_t fa0 = *(const bf16x8_t*)(&As[cur][wr * 32 + fl][fh * 8]);
        bf16x8_t fa1 = *(const bf16x8_t*)(&As[cur][wr * 32 + 16 + fl][fh * 8]);
        bf16x8_t fb0 = *(const bf16x8_t*)(&Bs[cur][wc * 32 + fl][fh * 8]);
        bf16x8_t fb1 = *(const bf16x8_t*)(&Bs[cur][wc * 32 + 16 + fl][fh * 8]);
        acc[0][0] = __builtin_amdgcn_mfma_f32_16x16x32_bf16(fa0, fb0, acc[0][0], 0, 0, 0);
        acc[0][1] = __builtin_amdgcn_mfma_f32_16x16x32_bf16(fa0, fb1, acc[0][1], 0, 0, 0);
        acc[1][0] = __builtin_amdgcn_mfma_f32_16x16x32_bf16(fa1, fb0, acc[1][0], 0, 0, 0);
        acc[1][1] = __builtin_amdgcn_mfma_f32_16x16x32_bf16(fa1, fb1, acc[1][1], 0, 0, 0);
        if (it + 1 < nk) {
            *(bf16x8_t*)(&As[cur ^ 1][srow][skoff]) = ra;
            *(bf16x8_t*)(&Bs[cur ^ 1][srow][skoff]) = rb;
            __syncthreads();
        }
    }

#pragma unroll
    for (int fi = 0; fi < 2; fi++)
#pragma unroll
        for (int fj = 0; fj < 2; fj++)
#pragma unroll
            for (int r = 0; r < 4; r++) {
                int m = row0 + wr * 32 + fi * 16 + fh * 4 + r;
                int n = col0 + wc * 32 + fj * 16 + fl;
                float v = acc[fi][fj][r];
                if (EPI == 0) {
                    if (n < N) ((float*)Cv)[co + (size_t)m * NC + n] = v;
                } else if (EPI == 1) {
                    if (n < NC) {
                        float o = 0.0f;
                        if (n < N) { o = v + bias[n]; o = 0.5f * o * (1.0f + erff(o * 0.70710678118654752f)); }
                        ((unsigned short*)Cv)[(size_t)m * NC + n] = f2bf(o);
                    }
                } else if (EPI == 2) {
                    if (n < N) {
                        v += bias[n];
                        ((float*)Cv)[(size_t)m * NC + n] = 1.0f / (1.0f + expf(-v));
                    }
                } else {
                    if (n < NC) {
                        ((unsigned short*)Cv)[co + (size_t)m * NC + n] = (n < N) ? f2bf(v) : (unsigned short)0;
                    }
                }
            }
}

// ---------------- glue kernels ----------------
__global__ void zero_masks_k(int* maskt, int* maskf) {
    int i = blockIdx.x * 256 + threadIdx.x;
    if (i < 2 * TDIM) maskt[i] = 0;
    if (i < PACK) maskf[i] = 0;
}

__global__ void tab_k(float* tabc, float* tabs) {
    int i = blockIdx.x * 256 + threadIdx.x;
    if (i >= 1024) return;
    double ang = (double)i * (3.14159265358979323846 * 2.0 / 1024.0);
    tabc[i] = (float)cos(ang);
    tabs[i] = (float)sin(ang);
}

__global__ void twid_fill_k(const float* __restrict__ tabc, const float* __restrict__ tabs,
                            float* __restrict__ Tw) {
    int row = blockIdx.x;
    for (int t = threadIdx.x; t < 1024; t += 256) {
        float v;
        if (row < NFREQ) v = tabc[(row * t) & 1023];
        else             v = -tabs[((row - NFREQ) * t) & 1023];
        Tw[(size_t)row * 1024 + t] = v;
    }
}

__global__ void itwid_fill_bf_k(const float* __restrict__ tabc, const float* __restrict__ tabs,
                                unsigned short* __restrict__ IT) {
    int t = blockIdx.x;
    for (int col = threadIdx.x; col < 1056; col += 256) {
        float v = 0.0f;
        if (col < NFREQ) {
            int k = col;
            float w = (k == 0 || k == 512) ? 1.0f : 2.0f;
            v = (w * (1.0f / 1024.0f)) * tabc[(k * t) & 1023];
        } else if (col < PACK) {
            int k = col - NFREQ;
            v = (k == 0 || k == 512) ? 0.0f : (-2.0f / 1024.0f) * tabs[(k * t) & 1023];
        }
        IT[(size_t)t * 1056 + col] = f2bf(v);
    }
}

// fused weight conversions (writes ALL pad zeros)
__global__ void conv_weights_k(const float* __restrict__ W1t, const float* __restrict__ W2t,
                               const float* __restrict__ W_emb,
                               unsigned short* __restrict__ w1b, unsigned short* __restrict__ w2b,
                               unsigned short* __restrict__ wemT) {
    int r = blockIdx.x;   // 0..1215
    if (r < 640) {
        int rr = r & 319;
        const float* src = (r < 320) ? W1t : W2t;
        unsigned short* dst = (r < 320) ? w1b : w2b;
        for (int c = threadIdx.x; c < 288; c += 256) {
            float v = (rr < DD && c < DD) ? src[(size_t)rr * DD + c] : 0.0f;
            dst[(size_t)rr * 288 + c] = f2bf(v);
        }
    } else {
        int rr = r - 640;  // 0..575
        for (int c = threadIdx.x; c < 288; c += 256) {
            float v = (rr < CC && c < DD) ? W_emb[(size_t)c * CC + rr] : 0.0f;
            wemT[(size_t)rr * 288 + c] = f2bf(v);
        }
    }
}

__global__ __launch_bounds__(64) void sliding_score_k(const float* __restrict__ ex,
                                                      double* __restrict__ score)
{
    const int ib = blockIdx.x;
    const int t = ib & (TDIM - 1);
    const int t0 = max(0, t - 24);
    const int nt = t - t0 + 1;
    const float cnt = (float)nt;
    const int lane = threadIdx.x;
    const float* base = ex + ((size_t)(ib - t) + t0) * DD;
    double ms = 0.0, vs = 0.0;
    for (int d = lane; d < DD; d += 64) {
        float s1 = 0.0f, s2 = 0.0f;
        for (int r = 0; r < nt; r++) {
            float v = base[(size_t)r * DD + d];
            s1 += v;
            s2 += v * v;
        }
        float m1 = s1 / cnt;
        float var = s2 / cnt - m1 * m1;
        ms += (double)m1;
        vs += (double)var;
    }
#pragma unroll
    for (int off = 32; off; off >>= 1) { ms += __shfl_xor(ms, off); vs += __shfl_xor(vs, off); }
    if (lane == 0) score[ib] = vs / (ms + (double)1e-6f);
}

__global__ __launch_bounds__(512) void topk_sort_k(const double* __restrict__ score,
                                                   int n, int kcount,
                                                   float* __restrict__ out_f,
                                                   int* __restrict__ out_i,
                                                   int* __restrict__ mask)
{
    __shared__ double sv[1024];
    __shared__ int    si[1024];
    const int b = blockIdx.x, tid = threadIdx.x;
    const double* s = score + (size_t)b * n;
    for (int i = tid; i < 1024; i += 512) {
        sv[i] = (i < n) ? s[i] : -1.0e300;
        si[i] = i;
    }
    __syncthreads();
    for (int k = 2; k <= 1024; k <<= 1) {
        for (int j = k >> 1; j > 0; j >>= 1) {
            for (int t = tid; t < 1024; t += 512) {
                int l = t ^ j;
                if (l > t) {
                    double v0 = sv[t], v1 = sv[l];
                    int i0 = si[t], i1 = si[l];
                    bool g = (v0 > v1) || (v0 == v1 && i0 < i1);
                    bool wrong = ((t & k) == 0) ? !g : g;
                    if (wrong) {
                        sv[t] = v1; sv[l] = v0;
                        si[t] = i1; si[l] = i0;
                    }
                }
            }
            __syncthreads();
        }
    }
    for (int t = tid; t < kcount; t += 512) {
        int bi = si[t];
        out_f[(size_t)b * kcount + t] = (float)bi;
        out_i[b * kcount + t] = bi;
        mask[b * n + bi] = 1;
    }
}

__global__ void build_masked_k(const float* __restrict__ ex, const float* __restrict__ ttok,
                               const int* __restrict__ maskt, unsigned short* __restrict__ mb) {
    int bt = blockIdx.x;
    int d = threadIdx.x;
    if (d >= 288) return;
    float v = 0.0f;
    if (d < DD) v = maskt[bt] ? ttok[d] : ex[(size_t)bt * DD + d];
    mb[(size_t)bt * 288 + d] = f2bf(v);
}

__global__ void select_k(const int* __restrict__ maskt, const float* __restrict__ proj,
                         unsigned short* __restrict__ mb) {
    int bt = blockIdx.x;
    int d = threadIdx.x;
    if (d >= DD) return;
    if (!maskt[bt]) mb[(size_t)bt * 288 + d] = f2bf(proj[(size_t)bt * DD + d]);
}

__global__ void mag_k(const float* __restrict__ cxp, double* __restrict__ magm) {
    int ib = blockIdx.x;
    int b = ib / NFREQ, k = ib % NFREQ;
    int lane = threadIdx.x;
    const float* re = cxp + ((size_t)b * PACK + k) * DD;
    const float* im = cxp + ((size_t)b * PACK + NFREQ + k) * DD;
    double acc = 0.0;
    for (int d = lane; d < DD; d += 64) {
        float r = re[d], i = im[d];
        acc += (double)sqrtf(r * r + i * i);
    }
#pragma unroll
    for (int off = 32; off; off >>= 1) acc += __shfl_xor(acc, off);
    if (lane == 0) magm[ib] = acc / (double)DD;
}

__global__ void fmask_apply_k(float* __restrict__ cxp, const int* __restrict__ idxf,
                              const float* __restrict__ tokr, const float* __restrict__ toki) {
    int b = blockIdx.x / KTOP, j = blockIdx.x % KTOP;
    int d = threadIdx.x;
    if (d >= DD) return;
    int k = idxf[b * KTOP + j];
    float* base = cxp + (size_t)b * PACK * DD;
    base[(size_t)k * DD + d] = tokr[d];
    base[(size_t)(NFREQ + k) * DD + d] = toki[d];
}

// cxp f32 [2][1026][263] -> cxpT bf16 [2][320][1056] (full fill incl. pads)
__global__ void conv_cxpT_k(const float* __restrict__ cxp, unsigned short* __restrict__ cxpT) {
    int b = blockIdx.x / 320, n = blockIdx.x % 320;
    unsigned short* dst = cxpT + ((size_t)b * 320 + n) * 1056;
    const float* src = cxp + (size_t)b * PACK * DD + n;
    for (int c = threadIdx.x; c < 1056; c += 256) {
        float v = (n < DD && c < PACK) ? src[(size_t)c * DD] : 0.0f;
        dst[c] = f2bf(v);
    }
}

// ---------------- launch ----------------
extern "C" void kernel_launch(void* const* d_in, const int* in_sizes, int n_in,
                              void* d_out, int out_size, void* d_ws, size_t ws_size,
                              hipStream_t stream) {
    (void)in_sizes; (void)n_in; (void)out_size;
    const float* x      = (const float*)d_in[0];
    const float* W_emb  = (const float*)d_in[1];
    const float* b_emb  = (const float*)d_in[2];
    const float* ttok   = (const float*)d_in[3];
    const float* W1t    = (const float*)d_in[4];
    const float* b1t    = (const float*)d_in[5];
    const float* W2t    = (const float*)d_in[6];
    const float* b2t    = (const float*)d_in[7];
    const float* ftr    = (const float*)d_in[8];
    const float* fti    = (const float*)d_in[9];
    float* out = (float*)d_out;
    float* ws  = (float*)d_ws;

    float* ex     = ws + WS_EX;
    float* proj   = ws + WS_PROJ;
    float* cxp    = ws + WS_CXP;
    float* Twid   = ws + WS_TWID;
    float* tabc   = ws + WS_TABC;
    float* tabs   = ws + WS_TABS;
    double* score = (double*)(ws + WS_SCORE);
    double* magm  = (double*)(ws + WS_MAGM);
    int* maskt    = (int*)(ws + WS_MASKT);
    int* idxt     = (int*)(ws + WS_IDXT);
    int* idxf     = (int*)(ws + WS_IDXF);
    int* maskf    = (int*)(ws + WS_MASKF);
    float* partw  = ws + WS_PART;
    unsigned short* w1b   = (unsigned short*)(ws + WS_W1BF);
    unsigned short* w2b   = (unsigned short*)(ws + WS_W2BF);
    unsigned short* wemT  = (unsigned short*)(ws + WS_WEMT);
    unsigned short* maskb = (unsigned short*)(ws + WS_MASKB);
    unsigned short* hb    = (unsigned short*)(ws + WS_HBF);
    unsigned short* xtb   = (unsigned short*)(ws + WS_XTBF);
    unsigned short* itb   = (unsigned short*)(ws + WS_ITBF);
    unsigned short* cxpT  = (unsigned short*)(ws + WS_CXPT);

    const bool big = ws_size >= (size_t)WS_TOTAL * 4;

    // init + tables + weight conversions
    zero_masks_k<<<8, 256, 0, stream>>>(maskt, maskf);
    tab_k<<<4, 256, 0, stream>>>(tabc, tabs);
    twid_fill_k<<<PACK, 256, 0, stream>>>(tabc, tabs, Twid);
    itwid_fill_bf_k<<<TDIM, 256, 0, stream>>>(tabc, tabs, itb);
    conv_weights_k<<<1216, 256, 0, stream>>>(W1t, W2t, W_emb, w1b, w2b, wemT);

    // ex = x @ W_emb^T + b_emb + pe  (f32 split-K 8x8; feeds both rankings)
    {
        int S = big ? 8 : 1;
        float* pp = big ? partw : ex;
        long MN = (long)2048 * DD;
        gemm_sk8<1><<<dim3(16, 3, S), 256, 0, stream>>>(x, W_emb, pp, 2048, DD, CC, S, 0, MN);
        reduce_k<3><<<(int)((MN + 255) / 256), 256, 0, stream>>>(pp, b_emb, ex, DD, S, MN, 0, MN);
    }

    // temporal score -> topk
    sliding_score_k<<<2048, 64, 0, stream>>>(ex, score);
    topk_sort_k<<<2, 512, 0, stream>>>(score, TDIM, KTOP, out + OFF_IDXT, idxt, maskt);

    // masked -> h -> proj -> select -> out_t   [value GEMMs: direct MFMA]
    build_masked_k<<<2048, 320, 0, stream>>>(ex, ttok, maskt, maskb);
    gemm_mfma<1><<<dim3(32, 5), 256, 0, stream>>>(maskb, w1b, b1t, hb, 263, 288, 288, 0, 0);
    gemm_mfma<2><<<dim3(32, 5), 256, 0, stream>>>(hb, w2b, b2t, proj, 263, 288, 263, 0, 0);
    select_k<<<2048, 320, 0, stream>>>(maskt, proj, maskb);
    gemm_mfma<0><<<dim3(32, 9), 256, 0, stream>>>(maskb, wemT, nullptr, out + OFF_OUTT,
                                                  526, 288, 526, 0, 0);

    // forward DFT (f32 split-K 8x8; feeds mag ranking): cxp[b] = Twid @ ex[b]
    {
        int S = big ? 8 : 1;
        float* pp = big ? partw : cxp;
        long MN = (long)PACK * DD;
        gemm_sk8<0><<<dim3(9, 3, 2 * S), 256, 0, stream>>>(Twid, ex, pp, PACK, DD, 1024, S,
                                                           (long)TDIM * DD, MN);
        reduce_k<0><<<(int)((2 * MN + 255) / 256), 256, 0, stream>>>(pp, nullptr, cxp, DD, S, MN, MN, 2 * MN);
    }
    mag_k<<<2 * NFREQ, 64, 0, stream>>>(cxp, magm);
    topk_sort_k<<<2, 512, 0, stream>>>(magm, NFREQ, KTOP, out + OFF_IDXF, idxf, maskf);
    fmask_apply_k<<<2 * KTOP, 320, 0, stream>>>(cxp, idxf, ftr, fti);
    conv_cxpT_k<<<640, 256, 0, stream>>>(cxp, cxpT);

    // inverse DFT (MFMA): xtb[b] = ITwid @ cxp[b]^T^T
    gemm_mfma<3><<<dim3(16, 5, 2), 256, 0, stream>>>(itb, cxpT, nullptr, xtb,
                                                     263, 1056, 288,
                                                     (long)320 * 1056, (long)1024 * 288);
    // out_f = xt @ W_emb
    gemm_mfma<0><<<dim3(32, 9), 256, 0, stream>>>(xtb, wemT, nullptr, out + OFF_OUTF,
                                                  526, 288, 526, 0, 0);
}